// Round 1
// baseline (12650.047 us; speedup 1.0000x reference)
//
#include <hip/hip_runtime.h>
#include <cmath>
#include <cstdint>

typedef __bf16 bf16;
typedef __bf16 bf16x8 __attribute__((ext_vector_type(8)));
typedef float f32x4 __attribute__((ext_vector_type(4)));

static __device__ __forceinline__ float gelu_exact(float x) {
    return 0.5f * x * (1.f + erff(x * 0.70710678118654752f));
}

// ---------- fp32 -> bf16 convert of x with SAME padding rows (t=-1 and t=2000 zeroed) ----------
// layout: xpad[b][tp][c], tp in [0,2002), xpad[b][tp] = x[b][tp-1] (zero at tp=0,2001)
__global__ void cvt_xpad_kernel(const float* __restrict__ x, bf16* __restrict__ xp) {
    int idx = blockIdx.x * 256 + threadIdx.x;
    if (idx >= 8 * 2002 * 128) return;
    int c = idx & 127;
    int rest = idx >> 7;            // b*2002 + tp
    int tp = rest % 2002;
    int b = rest / 2002;
    float v = 0.f;
    if (tp >= 1 && tp <= 2000) v = x[(b * 2000 + tp - 1) * 128 + c];
    xp[idx] = (bf16)v;
}

// ---------- generic transpose+convert: in fp32 [R][C] -> out [C][Rpad], zero pad r in [R,Rpad) ----------
template <typename OT>
__global__ void transpose_cvt_kernel(const float* __restrict__ in, OT* __restrict__ out,
                                     int R, int C, int Rpad) {
    __shared__ float tile[32][33];
    int tx = threadIdx.x & 31, ty = threadIdx.x >> 5;   // 32 x 8
    int r0 = blockIdx.y * 32, c0 = blockIdx.x * 32;
    for (int i = ty; i < 32; i += 8) {
        int r = r0 + i, c = c0 + tx;
        tile[i][tx] = (r < R && c < C) ? in[(size_t)r * C + c] : 0.f;
    }
    __syncthreads();
    for (int i = ty; i < 32; i += 8) {
        int c = c0 + i, r = r0 + tx;
        if (c < C && r < Rpad) out[(size_t)c * Rpad + r] = (OT)tile[tx][i];
    }
}

// ---------- zero h1 pad row (t=2000 per batch) + h/c state buffers ----------
__global__ void zero_aux_kernel(bf16* __restrict__ h1, float* __restrict__ hc) {
    int idx = blockIdx.x * 256 + threadIdx.x;
    if (idx < 8 * 4096) {
        int b = idx >> 12, n = idx & 4095;
        h1[((size_t)(b * 2001 + 2000)) * 4096 + n] = (bf16)0.f;
    }
    int j = idx - 8 * 4096;
    if (j >= 0 && j < 3 * 4096) hc[j] = 0.f;   // hbuf[2][4096] + cbuf[4096], contiguous
}

// ---------- unified bf16 MFMA GEMM, 128x128 tile, BK=32, 256 thr (4 waves, each 64x64) ----------
// MODE 0: conv1  M=16000(b,t)    K=384  (tap,cin)  N=4096  A=xpad[b][t+tap][c]      out: gelu -> h1 bf16 [b][t][n]
// MODE 1: conv2  M=8000 (b,t')   K=12288(tap,cin)  N=1024  A=h1[b][2t'+tap][c]      out: gelu -> h2T bf16 [b][n][t']
// MODE 2: zin    M=8192 (b,s)    K=1024 (f,pad)    N=2048  A=h2T[b][s][f]           out: +bias -> Zin fp32 [b][s][n]
template <int MODE>
__launch_bounds__(256)
__global__ void gemm_kernel(const bf16* __restrict__ A, const bf16* __restrict__ BT,
                            const float* __restrict__ bias, void* __restrict__ Cout) {
    constexpr int KTOT = (MODE == 0) ? 384 : (MODE == 1) ? 12288 : 1024;
    constexpr int MTOT = (MODE == 0) ? 16000 : (MODE == 1) ? 8000 : 8192;
    __shared__ __align__(16) bf16 As[128 * 32];
    __shared__ __align__(16) bf16 Bs[128 * 32];
    const int tid = threadIdx.x;
    const int lane = tid & 63, wave = tid >> 6;
    const int m0 = blockIdx.y * 128, n0 = blockIdx.x * 128;
    const int wm = (wave >> 1) * 64, wn = (wave & 1) * 64;

    f32x4 acc[4][4];
#pragma unroll
    for (int mi = 0; mi < 4; ++mi)
#pragma unroll
        for (int ni = 0; ni < 4; ++ni) acc[mi][ni] = (f32x4){0.f, 0.f, 0.f, 0.f};

    for (int kt = 0; kt < KTOT / 32; ++kt) {
        const int k0 = kt * 32;
        __syncthreads();
#pragma unroll
        for (int s = 0; s < 2; ++s) {
            int ch = tid + s * 256;          // 512 chunks of 16B = 8KB tile
            int row = ch >> 2;
            int ko = (ch & 3) * 8;
            int m = m0 + row;
            if (m > MTOT - 1) m = MTOT - 1;
            const bf16* ga;
            if (MODE == 0) {
                int b = m / 2000, t = m - b * 2000;
                ga = A + ((size_t)(b * 2002 + t + (k0 >> 7)) * 128 + (k0 & 127) + ko);
            } else if (MODE == 1) {
                int b = m / 1000, t = m - b * 1000;
                ga = A + ((size_t)(b * 2001 + 2 * t + (k0 >> 12)) * 4096 + (k0 & 4095) + ko);
            } else {
                ga = A + ((size_t)m * 1000 + k0 + ko);   // overruns row end by <=24 elems; B rows are zero there
            }
            *(uint4*)&As[ch * 8] = *(const uint4*)ga;
            const bf16* gb = BT + ((size_t)(n0 + row) * KTOT + k0 + ko);
            *(uint4*)&Bs[ch * 8] = *(const uint4*)gb;
        }
        __syncthreads();
        bf16x8 af[4], bfr[4];
#pragma unroll
        for (int i = 0; i < 4; ++i)
            af[i] = *(const bf16x8*)&As[(wm + i * 16 + (lane & 15)) * 32 + (lane >> 4) * 8];
#pragma unroll
        for (int i = 0; i < 4; ++i)
            bfr[i] = *(const bf16x8*)&Bs[(wn + i * 16 + (lane & 15)) * 32 + (lane >> 4) * 8];
#pragma unroll
        for (int mi = 0; mi < 4; ++mi)
#pragma unroll
            for (int ni = 0; ni < 4; ++ni)
                acc[mi][ni] = __builtin_amdgcn_mfma_f32_16x16x32_bf16(af[mi], bfr[ni], acc[mi][ni], 0, 0, 0);
    }

#pragma unroll
    for (int mi = 0; mi < 4; ++mi) {
        int rb = m0 + wm + mi * 16 + (lane >> 4) * 4;
#pragma unroll
        for (int ni = 0; ni < 4; ++ni) {
            int col = n0 + wn + ni * 16 + (lane & 15);
#pragma unroll
            for (int i = 0; i < 4; ++i) {
                int row = rb + i;
                float v = acc[mi][ni][i];
                if (MODE == 0) {
                    float y = gelu_exact(v + bias[col]);
                    int b = row / 2000, t = row - b * 2000;
                    ((bf16*)Cout)[(size_t)(b * 2001 + t) * 4096 + col] = (bf16)y;
                } else if (MODE == 1) {
                    if (row < 8000) {
                        float y = gelu_exact(v + bias[col]);
                        int b = row / 1000, t = row - b * 1000;
                        ((bf16*)Cout)[(size_t)(b * 1024 + col) * 1000 + t] = (bf16)y;
                    }
                } else {
                    ((float*)Cout)[(size_t)row * 2048 + col] = v + bias[col];
                }
            }
        }
    }
}

// ---------- one LSTM time step: z = Zin[:,t,:] + h_in @ Wr ; gates ; write h_out, c, out ----------
// grid 128 wgs x 256 thr; wg owns hidden units [4*wg, 4*wg+4), wave u -> unit j, all 8 batches
__launch_bounds__(256)
__global__ void lstm_step_kernel(const float* __restrict__ Zin, const float* __restrict__ WrT,
                                 const float* __restrict__ h_in, float* __restrict__ h_out,
                                 float* __restrict__ c_buf, float* __restrict__ out, int t) {
    __shared__ float hs[4096];   // h_in[8][512]
    const int tid = threadIdx.x;
    for (int i = tid; i < 4096; i += 256) hs[i] = h_in[i];
    __syncthreads();
    const int lane = tid & 63, wave = tid >> 6;
    const int j = blockIdx.x * 4 + wave;    // hidden unit 0..511
    float acc[32];
#pragma unroll
    for (int i = 0; i < 32; ++i) acc[i] = 0.f;
#pragma unroll
    for (int it = 0; it < 8; ++it) {
        int k = it * 64 + lane;
        float w0 = WrT[(0 * 512 + j) * 512 + k];
        float w1 = WrT[(1 * 512 + j) * 512 + k];
        float w2 = WrT[(2 * 512 + j) * 512 + k];
        float w3 = WrT[(3 * 512 + j) * 512 + k];
#pragma unroll
        for (int b = 0; b < 8; ++b) {
            float h = hs[b * 512 + k];
            acc[b * 4 + 0] += h * w0;
            acc[b * 4 + 1] += h * w1;
            acc[b * 4 + 2] += h * w2;
            acc[b * 4 + 3] += h * w3;
        }
    }
#pragma unroll
    for (int off = 32; off > 0; off >>= 1)
#pragma unroll
        for (int i = 0; i < 32; ++i) acc[i] += __shfl_xor(acc[i], off, 64);
    if (lane < 8) {
        const int b = lane;
        const float* zp = Zin + ((size_t)(b * 1024 + t)) * 2048;
        float zi = acc[b * 4 + 0] + zp[j];
        float zf = acc[b * 4 + 1] + zp[512 + j];
        float zg = acc[b * 4 + 2] + zp[1024 + j];
        float zo = acc[b * 4 + 3] + zp[1536 + j];
        float ig = 1.f / (1.f + expf(-zi));
        float fg = 1.f / (1.f + expf(-zf));
        float og = 1.f / (1.f + expf(-zo));
        float c = fg * c_buf[b * 512 + j] + ig * tanhf(zg);
        float h = og * tanhf(c);
        c_buf[b * 512 + j] = c;
        h_out[b * 512 + j] = h;
        float expo = (float)(2 * (j >> 1)) * (1.f / 512.f);
        float ang = (float)t * powf(10000.f, -expo);
        float pe = (j & 1) ? cosf(ang) : sinf(ang);
        out[((size_t)(b * 1024 + t)) * 512 + j] = h + pe;
    }
}

extern "C" void kernel_launch(void* const* d_in, const int* in_sizes, int n_in,
                              void* d_out, int out_size, void* d_ws, size_t ws_size,
                              hipStream_t stream) {
    const float* x  = (const float*)d_in[0];
    const float* w1 = (const float*)d_in[1];
    const float* b1 = (const float*)d_in[2];
    const float* w2 = (const float*)d_in[3];
    const float* b2 = (const float*)d_in[4];
    const float* wk = (const float*)d_in[5];
    const float* wr = (const float*)d_in[6];
    const float* lb = (const float*)d_in[7];
    float* out = (float*)d_out;

    // workspace layout (~255.5 MB total)
    uint8_t* ws = (uint8_t*)d_ws;
    size_t off = 0;
    auto alloc = [&](size_t bytes) {
        void* p = ws + off;
        off += (bytes + 255) & ~(size_t)255;
        return p;
    };
    bf16* xpad = (bf16*)alloc((size_t)8 * 2002 * 128 * 2);
    bf16* W1T  = (bf16*)alloc((size_t)4096 * 384 * 2);
    bf16* W2T  = (bf16*)alloc((size_t)1024 * 12288 * 2);
    bf16* WkT  = (bf16*)alloc((size_t)2048 * 1024 * 2);
    float* WrT = (float*)alloc((size_t)2048 * 512 * 4);
    bf16* h1   = (bf16*)alloc((size_t)8 * 2001 * 4096 * 2);
    bf16* h2T  = (bf16*)alloc((size_t)8 * 1024 * 1000 * 2 + 256);  // +slack for k-tail overread
    float* Zin = (float*)alloc((size_t)8 * 1024 * 2048 * 4);
    float* hbuf = (float*)alloc((size_t)3 * 4096 * 4);  // hbuf[2][4096] + cbuf[4096]
    float* cbuf = hbuf + 2 * 4096;

    cvt_xpad_kernel<<<(8 * 2002 * 128 + 255) / 256, 256, 0, stream>>>(x, xpad);
    transpose_cvt_kernel<bf16><<<dim3(128, 12), 256, 0, stream>>>(w1, W1T, 384, 4096, 384);
    transpose_cvt_kernel<bf16><<<dim3(32, 384), 256, 0, stream>>>(w2, W2T, 12288, 1024, 12288);
    transpose_cvt_kernel<bf16><<<dim3(64, 32), 256, 0, stream>>>(wk, WkT, 1000, 2048, 1024);
    transpose_cvt_kernel<float><<<dim3(64, 16), 256, 0, stream>>>(wr, WrT, 512, 2048, 512);
    zero_aux_kernel<<<(8 * 4096 + 3 * 4096 + 255) / 256, 256, 0, stream>>>(h1, hbuf);

    gemm_kernel<0><<<dim3(32, 125), 256, 0, stream>>>(xpad, W1T, b1, (void*)h1);
    gemm_kernel<1><<<dim3(8, 63), 256, 0, stream>>>(h1, W2T, b2, (void*)h2T);
    gemm_kernel<2><<<dim3(16, 64), 256, 0, stream>>>(h2T, WkT, lb, (void*)Zin);

    for (int t = 0; t < 1024; ++t) {
        const float* hin = hbuf + (t & 1) * 4096;
        float* hout = hbuf + ((t + 1) & 1) * 4096;
        lstm_step_kernel<<<128, 256, 0, stream>>>(Zin, WrT, hin, hout, cbuf, out, t);
    }
}